// Round 1
// 668.339 us; speedup vs baseline: 1.0428x; 1.0428x over previous
//
#include <hip/hip_runtime.h>
#include <math.h>

#define V 50000
#define E 300
#define H 2048
#define L 512
#define EH 2348  // E+H

// ---------------- kernel 1: attention scores = cat(emb_row, h0) @ attn_W.T + attn_b
// Also zeroes attnap (blocks 0..7) so k_smax_apply can atomicAdd into it.
__global__ void k_attn_scores(const int* __restrict__ token, const float* __restrict__ h0,
                              const float* __restrict__ emb, const float* __restrict__ attn_W,
                              const float* __restrict__ attn_b, float* __restrict__ scores,
                              float* __restrict__ attnap) {
    int row = blockIdx.x;
    int tid = threadIdx.x;
    if (row < 8) attnap[row * 256 + tid] = 0.f;   // 8*256 == H
    const float* erow = emb + (size_t)token[0] * E;
    const float* wrow = attn_W + (size_t)row * EH;
    float acc = 0.f;
    for (int j = tid; j < EH; j += 256) {
        float c = (j < E) ? erow[j] : h0[j - E];
        acc += c * wrow[j];
    }
    __shared__ float red[256];
    red[tid] = acc; __syncthreads();
    for (int s = 128; s > 0; s >>= 1) {
        if (tid < s) red[tid] += red[tid + s];
        __syncthreads();
    }
    if (tid == 0) scores[row] = red[0] + attn_b[row];
}

// ---------------- kernel 2: fused softmax + attn_apply
// grid = 64 blocks: hgroup = bx&7 (256 h cols), lchunk = bx>>3 (64 l rows).
// Each block redundantly computes the full softmax over 512 scores (L2-hot),
// applies its l-chunk, atomicAdds the partial into attnap. Block 0 also emits
// the attn_weights output.
__global__ void k_smax_apply(const float* __restrict__ scores, const float* __restrict__ enc,
                             float* __restrict__ attnap, float* __restrict__ out_attnw) {
    int tid = threadIdx.x;
    int hgroup = blockIdx.x & 7;
    int lchunk = blockIdx.x >> 3;
    __shared__ float e[L];
    __shared__ float red[256];
    float v0 = scores[tid], v1 = scores[tid + 256];
    red[tid] = fmaxf(v0, v1); __syncthreads();
    for (int s = 128; s > 0; s >>= 1) { if (tid < s) red[tid] = fmaxf(red[tid], red[tid + s]); __syncthreads(); }
    float m = red[0]; __syncthreads();
    float e0 = expf(v0 - m), e1 = expf(v1 - m);
    e[tid] = e0; e[tid + 256] = e1;
    red[tid] = e0 + e1; __syncthreads();
    for (int s = 128; s > 0; s >>= 1) { if (tid < s) red[tid] += red[tid + s]; __syncthreads(); }
    float inv = 1.f / red[0];

    int hbase = hgroup * 256;
    int l0 = lchunk * 64;
    float acc = 0.f;
    #pragma unroll 8
    for (int l = 0; l < 64; ++l)
        acc += e[l0 + l] * enc[(size_t)(l0 + l) * H + hbase + tid];
    atomicAdd(&attnap[hbase + tid], acc * inv);

    if (blockIdx.x == 0) {
        out_attnw[tid]       = e[tid] * inv;
        out_attnw[tid + 256] = e[tid + 256] * inv;
    }
}

// ---------------- kernel 3: x = relu(cat(emb_row, attn_applied) @ comb_W.T + comb_b)
__global__ void k_combine(const int* __restrict__ token, const float* __restrict__ emb,
                          const float* __restrict__ attn_applied, const float* __restrict__ comb_W,
                          const float* __restrict__ comb_b, float* __restrict__ x) {
    int row = blockIdx.x;
    int tid = threadIdx.x;
    const float* erow = emb + (size_t)token[0] * E;
    const float* wrow = comb_W + (size_t)row * EH;
    float acc = 0.f;
    for (int j = tid; j < EH; j += 256) {
        float c = (j < E) ? erow[j] : attn_applied[j - E];
        acc += c * wrow[j];
    }
    __shared__ float red[256];
    red[tid] = acc; __syncthreads();
    for (int s = 128; s > 0; s >>= 1) {
        if (tid < s) red[tid] += red[tid + s];
        __syncthreads();
    }
    if (tid == 0) x[row] = fmaxf(red[0] + comb_b[row], 0.f);
}

// ---------------- kernel 4: fused GRU input+hidden GEMV, wave-per-2-rows, float4
__global__ void k_gru_gemv(const float* __restrict__ x, const float* __restrict__ h0,
                           const float* __restrict__ W_ih, const float* __restrict__ W_hh,
                           const float* __restrict__ b_ih, const float* __restrict__ b_hh,
                           float* __restrict__ gi, float* __restrict__ gh) {
    int lane = threadIdx.x & 63;
    int wave = (blockIdx.x * blockDim.x + threadIdx.x) >> 6;
    int nw = (gridDim.x * blockDim.x) >> 6;
    const float4* x4 = (const float4*)x;
    const float4* h4 = (const float4*)h0;
    float4 xr[8], hr[8];
    #pragma unroll
    for (int i = 0; i < 8; i++) { xr[i] = x4[i * 64 + lane]; hr[i] = h4[i * 64 + lane]; }
    // rows are processed in even pairs; 3H boundary (6144) is even so a pair
    // never straddles the W_ih / W_hh split.
    for (int r = wave * 2; r < 2 * 3 * H; r += nw * 2) {
        bool is_i = r < 3 * H;               // wave-uniform branch
        int row = is_i ? r : r - 3 * H;
        const float* Wb = is_i ? W_ih : W_hh;
        const float4* w0 = (const float4*)(Wb + (size_t)row * H);
        const float4* w1 = (const float4*)(Wb + (size_t)(row + 1) * H);
        float a0 = 0.f, a1 = 0.f;
        #pragma unroll
        for (int i = 0; i < 8; i++) {
            float4 p = w0[i * 64 + lane];
            float4 q = w1[i * 64 + lane];
            float4 v = is_i ? xr[i] : hr[i];
            a0 += v.x * p.x + v.y * p.y + v.z * p.z + v.w * p.w;
            a1 += v.x * q.x + v.y * q.y + v.z * q.z + v.w * q.w;
        }
        #pragma unroll
        for (int off = 32; off > 0; off >>= 1) {
            a0 += __shfl_xor(a0, off, 64);
            a1 += __shfl_xor(a1, off, 64);
        }
        if (lane == 0) {
            float* dst = is_i ? gi : gh;
            const float* b = is_i ? b_ih : b_hh;
            dst[row]     = a0 + b[row];
            dst[row + 1] = a1 + b[row + 1];
        }
    }
}

// ---------------- kernel 5: GRU elementwise -> h_new (written directly to d_out slot)
__global__ void k_gru_elem(const float* __restrict__ gi, const float* __restrict__ gh,
                           const float* __restrict__ h0, float* __restrict__ hnew) {
    int h = blockIdx.x * 256 + threadIdx.x;
    float r = 1.f / (1.f + expf(-(gi[h] + gh[h])));
    float z = 1.f / (1.f + expf(-(gi[H + h] + gh[H + h])));
    float n = tanhf(gi[2 * H + h] + r * gh[2 * H + h]);
    hnew[h] = (1.f - z) * n + z * h0[h];
}

// ---------------- kernel 6: logits = h_new @ out_W.T + out_b (410 MB GEMV), 2 rows/wave
__global__ void k_out_gemv(const float* __restrict__ hnew, const float* __restrict__ out_W,
                           const float* __restrict__ out_b, float* __restrict__ logits) {
    int lane = threadIdx.x & 63;
    int wave = (blockIdx.x * blockDim.x + threadIdx.x) >> 6;
    int nw = (gridDim.x * blockDim.x) >> 6;
    const float4* h4 = (const float4*)hnew;
    float4 hreg[8];
    #pragma unroll
    for (int i = 0; i < 8; i++) hreg[i] = h4[i * 64 + lane];
    // V = 50000 is even; r starts even and strides by 2*nw, so r+1 < V whenever r < V.
    for (int r = wave * 2; r < V; r += nw * 2) {
        const float4* w0 = (const float4*)(out_W + (size_t)r * H);
        const float4* w1 = (const float4*)(out_W + (size_t)(r + 1) * H);
        float a0 = 0.f, a1 = 0.f;
        #pragma unroll
        for (int i = 0; i < 8; i++) {
            float4 p = w0[i * 64 + lane];
            float4 q = w1[i * 64 + lane];
            a0 += hreg[i].x * p.x + hreg[i].y * p.y + hreg[i].z * p.z + hreg[i].w * p.w;
            a1 += hreg[i].x * q.x + hreg[i].y * q.y + hreg[i].z * q.z + hreg[i].w * q.w;
        }
        #pragma unroll
        for (int off = 32; off > 0; off >>= 1) {
            a0 += __shfl_xor(a0, off, 64);
            a1 += __shfl_xor(a1, off, 64);
        }
        if (lane == 0) {
            logits[r]     = a0 + out_b[r];
            logits[r + 1] = a1 + out_b[r + 1];
        }
    }
}

// ---------------- kernel 7: per-block online logsumexp partials (64 blocks)
__global__ void k_lse_part(const float* __restrict__ logits, float2* __restrict__ part) {
    int tid = threadIdx.x;
    int idx = blockIdx.x * 256 + tid;
    const int stride = 64 * 256;
    float m = -1e30f, s = 0.f;
    for (int i = idx; i < V; i += stride) {
        float xv = logits[i];
        if (xv > m) { s = s * expf(m - xv) + 1.f; m = xv; }
        else        { s += expf(xv - m); }
    }
    __shared__ float mred[256], sred[256];
    mred[tid] = m; sred[tid] = s; __syncthreads();
    for (int st = 128; st > 0; st >>= 1) {
        if (tid < st) {
            float m2 = mred[tid + st], s2 = sred[tid + st];
            float mm = fmaxf(mred[tid], m2);
            sred[tid] = sred[tid] * expf(mred[tid] - mm) + s2 * expf(m2 - mm);
            mred[tid] = mm;
        }
        __syncthreads();
    }
    if (tid == 0) part[blockIdx.x] = make_float2(mred[0], sred[0]);
}

// ---------------- kernel 8: final log_softmax write (fused final LSE reduce of 64 partials)
__global__ void k_logsoftmax(const float* __restrict__ logits, const float2* __restrict__ part,
                             float* __restrict__ out) {
    __shared__ float mred[64], sred[64];
    __shared__ float Csh;
    int tid = threadIdx.x;
    if (tid < 64) { float2 p = part[tid]; mred[tid] = p.x; sred[tid] = p.y; }
    __syncthreads();
    for (int st = 32; st > 0; st >>= 1) {
        if (tid < st) {
            float m2 = mred[tid + st], s2 = sred[tid + st];
            float mm = fmaxf(mred[tid], m2);
            sred[tid] = sred[tid] * expf(mred[tid] - mm) + s2 * expf(m2 - mm);
            mred[tid] = mm;
        }
        __syncthreads();
    }
    if (tid == 0) Csh = mred[0] + logf(sred[0]);
    __syncthreads();
    float C = Csh;
    int i = blockIdx.x * 256 + tid;
    if (i < V) out[i] = logits[i] - C;
}

extern "C" void kernel_launch(void* const* d_in, const int* in_sizes, int n_in,
                              void* d_out, int out_size, void* d_ws, size_t ws_size,
                              hipStream_t stream) {
    const int*   token  = (const int*)d_in[0];
    const float* hidden = (const float*)d_in[1];   // [1,1,H]
    const float* enc    = (const float*)d_in[2];   // [L,H]
    const float* emb    = (const float*)d_in[3];   // [V,E]
    const float* attn_W = (const float*)d_in[4];   // [L,EH]
    const float* attn_b = (const float*)d_in[5];   // [L]
    const float* comb_W = (const float*)d_in[6];   // [H,EH]
    const float* comb_b = (const float*)d_in[7];   // [H]
    const float* W_ih   = (const float*)d_in[8];   // [3H,H]
    const float* W_hh   = (const float*)d_in[9];   // [3H,H]
    const float* b_ih   = (const float*)d_in[10];  // [3H]
    const float* b_hh   = (const float*)d_in[11];  // [3H]
    const float* out_W  = (const float*)d_in[12];  // [V,H]
    const float* out_b  = (const float*)d_in[13];  // [V]

    float* out = (float*)d_out;
    float* ws  = (float*)d_ws;

    // ws layout (floats)
    float* scores = ws;            // 512
    float* attnap = ws + 1024;     // 2048
    float* xvec   = ws + 4096;     // 2048
    float* gi     = ws + 8192;     // 6144
    float* gh     = ws + 14336;    // 6144
    float* logits = ws + 20480;    // 50000
    float2* part  = (float2*)(ws + 70528); // 64 float2 = 128 floats

    // d_out layout: output[50000] | h_new[2048] | attn_weights[512]
    float* out_logits = out;
    float* out_h      = out + V;
    float* out_attnw  = out + V + H;

    k_attn_scores<<<512, 256, 0, stream>>>(token, hidden, emb, attn_W, attn_b, scores, attnap);
    k_smax_apply<<<64, 256, 0, stream>>>(scores, enc, attnap, out_attnw);
    k_combine<<<2048, 256, 0, stream>>>(token, emb, attnap, comb_W, comb_b, xvec);
    k_gru_gemv<<<512, 256, 0, stream>>>(xvec, hidden, W_ih, W_hh, b_ih, b_hh, gi, gh);
    k_gru_elem<<<8, 256, 0, stream>>>(gi, gh, hidden, out_h);
    k_out_gemv<<<2048, 256, 0, stream>>>(out_h, out_W, out_b, logits);
    k_lse_part<<<64, 256, 0, stream>>>(logits, part);
    k_logsoftmax<<<196, 256, 0, stream>>>(logits, part, out_logits);
}